// Round 6
// baseline (246.341 us; speedup 1.0000x reference)
//
#include <hip/hip_runtime.h>
#include <hip/hip_bf16.h>
#include <math.h>

// SphConv: B=64, n=32, C_in=C_out=128, L=16, (l,m) pairs l>=m: 136.
// Three plain launches (cooperative launch breaks this harness's graph
// capture — R5 post-mortem):
//   k_init: tables (memoized via g_tab_ready)
//   k_fwd : FFT(phi) + MFMA Legendre analysis -> coef split re/im planes
//           in d_ws; W->Wt[l][o][c] bf16 transpose tail on blks<512
//   k_cbf : blk=(b,oq,jh): MFMA channel-GEMM (A-frags load b128 directly
//           from split planes, no unpack) -> chs LDS [ol][pair], then
//           Legendre synthesis + iDFT + bias, 2 j/thread.
// bf16 pack points identical to R4 -> identical numerics.

#define NPAIR 136
#define PADC 140            // pair-minor row stride (136 + 4 pad)
#define PIM_U (1u << 20)    // im-plane offset in uints (4 MB)
#define WT_OFF (8u << 20)   // byte offset of Wt[l][o][c] bf16 in d_ws
#define SMEM_BYTES 35328    // max(phaseA: 16896+18432, phaseB: 17920+8960)

typedef __attribute__((ext_vector_type(8))) short short8;
typedef __attribute__((ext_vector_type(4))) float f32x4;
#define MFMA16(A, B, C) __builtin_amdgcn_mfma_f32_16x16x32_bf16(A, B, C, 0, 0, 0)

static __device__ __forceinline__ float us2f(unsigned int u) {
  union { unsigned int i; float f; } v; v.i = u << 16; return v.f;
}
static __device__ __forceinline__ unsigned short f2us(float f) {
  __hip_bfloat16 h = __float2bfloat16(f);
  return *(unsigned short*)&h;
}
static __device__ __forceinline__ float lo_f(unsigned int pk) {
  union { unsigned int i; float f; } v; v.i = pk << 16; return v.f;
}
static __device__ __forceinline__ float hi_f(unsigned int pk) {
  union { unsigned int i; float f; } v; v.i = pk & 0xffff0000u; return v.f;
}
static __device__ __forceinline__ unsigned int packbf(float a, float b) {
  return (unsigned int)f2us(a) | ((unsigned int)f2us(b) << 16);
}

__device__ __align__(16) unsigned short g_atab_h[NPAIR * 32]; // bf16 Q*wj
__device__ __align__(16) float          g_stab[32 * PADC];    // fp32 Q*scale*(m?2:1), [j][pair]
__device__ int g_tab_ready;                                   // tables memoized across runs

static __device__ __forceinline__ int detect_fp32(const void* xin) {
  const unsigned short* u = (const unsigned short*)xin;
  int lane = threadIdx.x & 63;
  int big = 0;
#pragma unroll
  for (int q = 0; q < 4; ++q) {
    float v = us2f((unsigned int)u[lane * 8 + q * 2]);
    if (!(fabsf(v) <= 1e3f)) big = 1;
  }
  unsigned long long mask = __ballot(big);
  return (__popcll(mask) >= 16) ? 1 : 0;
}

// 32-pt DFT trig tables, cos/sin(2*pi*k/32) — compile-time indices only
#define DEF_TRIG \
  constexpr float CT[32] = { \
    1.0f, 0.98078528f, 0.92387953f, 0.83146961f, 0.70710678f, 0.55557023f, \
    0.38268343f, 0.19509032f, 0.0f, -0.19509032f, -0.38268343f, -0.55557023f, \
    -0.70710678f, -0.83146961f, -0.92387953f, -0.98078528f, -1.0f, \
    -0.98078528f, -0.92387953f, -0.83146961f, -0.70710678f, -0.55557023f, \
    -0.38268343f, -0.19509032f, 0.0f, 0.19509032f, 0.38268343f, 0.55557023f, \
    0.70710678f, 0.83146961f, 0.92387953f, 0.98078528f }; \
  constexpr float ST[32] = { \
    0.0f, 0.19509032f, 0.38268343f, 0.55557023f, 0.70710678f, 0.83146961f, \
    0.92387953f, 0.98078528f, 1.0f, 0.98078528f, 0.92387953f, 0.83146961f, \
    0.70710678f, 0.55557023f, 0.38268343f, 0.19509032f, 0.0f, \
    -0.19509032f, -0.38268343f, -0.55557023f, -0.70710678f, -0.83146961f, \
    -0.92387953f, -0.98078528f, -1.0f, -0.98078528f, -0.92387953f, \
    -0.83146961f, -0.70710678f, -0.55557023f, -0.38268343f, -0.19509032f }

// ---------------------------------------------------------------------------
// Table compute for one (pair, j) — fp64, input-independent.
// ---------------------------------------------------------------------------
static __device__ void tab_compute(int pair, int j) {
  int m = 0;
#pragma unroll
  for (int mm = 1; mm < 16; ++mm) {
    int off = mm * 16 - (mm * (mm - 1)) / 2;
    if (off <= pair) m = mm;
  }
  const int l = m + (pair - (m * 16 - (m * (m - 1)) / 2));
  double theta = M_PI * (j + 0.5) / 32.0;
  double x = cos(theta), sx = sin(theta);
  double wj = sx * (M_PI / 32.0) * (2.0 * M_PI / 32.0);
  double pmm = 1.0;
  for (int k = 1; k <= m; ++k) pmm *= -(2.0 * k - 1.0) * sx;
  double p = pmm, pl1 = 0.0, pl2 = 0.0;
  for (int ll = m; ll <= l; ++ll) {
    if (ll == m)          p = pmm;
    else if (ll == m + 1) p = (2.0 * m + 1.0) * x * pmm;
    else                  p = ((2.0 * ll - 1.0) * x * pl1 - (double)(ll + m - 1) * pl2) / (double)(ll - m);
    pl2 = pl1; pl1 = p;
  }
  double r = 1.0;
  for (int k = l - m + 1; k <= l + m; ++k) r *= (double)k;   // (l+m)!/(l-m)!
  double Nlm = sqrt((2.0 * l + 1.0) / (4.0 * M_PI) / r);
  g_atab_h[pair * 32 + j] = f2us((float)(Nlm * p * wj));
  g_stab[j * PADC + pair] = (float)(Nlm * p * (2.0 * M_PI * sqrt(4.0 * M_PI / (2.0 * l + 1.0)))
                                    * (m ? 2.0 : 1.0));
}

// ---------------------------------------------------------------------------
// K0: tables. One block per (l,m) pair x 32 j. Memoized via g_tab_ready.
// ---------------------------------------------------------------------------
__global__ void k_init() {
  if (g_tab_ready) return;
  tab_compute(blockIdx.x, threadIdx.x);
  if (blockIdx.x == NPAIR - 1 && threadIdx.x == 31) g_tab_ready = 1;
}

// ---------------------------------------------------------------------------
// K1: FFT(phi) + MFMA Legendre analysis. blk=(b XCD-swizzled, cq).
// Phase 1: one (j,c) DFT per thread -> fsp2[m][n=2c+ri][j] u16.
// Phase 2: MFMA per m (wave wv handles m=wv*4..+3): A=atab (LDS, staged
// into dead xs region), B=fsp2; D -> coef split planes:
// plane_re[b][pair][w] / plane_im (+PIM_U), word w = channels {2w, 2w+1}
// (lane n pairs with lane n^2 via shfl_xor at identical f2us points).
// Tail (blk<512): W -> Wt[l][o][c] bf16 transpose (per-call, W varies).
// ---------------------------------------------------------------------------
__global__ __launch_bounds__(256) void k_fwd(const void* __restrict__ xin,
                                             unsigned int* __restrict__ ws,
                                             const void* __restrict__ Wv) {
  const int fp32m = detect_fp32(xin);
  __shared__ __align__(16) char smem[SMEM_BYTES];
  unsigned short* xs   = (unsigned short*)smem;            // [p][j*8+c]; atab after ph1
  unsigned short* fsp2 = xs + 32 * 264;                    // [m][n][j] 18 KB
  const int blk = blockIdx.x;
  const int b = (blk & 7) | (((blk >> 7) & 7) << 3);       // same-b -> same XCD
  const int cq = (blk >> 3) & 15;                          // 8-channel group
  const int t = threadIdx.x;
  // prefetch atab (544 uint4) into registers — latency hides under phase 1
  uint4 at0 = ((const uint4*)g_atab_h)[t];
  uint4 at1 = ((const uint4*)g_atab_h)[t + 256];
  uint4 at2;
  if (t < 32) at2 = ((const uint4*)g_atab_h)[512 + t];
  // W -> Wt transpose tail work, distributed over blocks 0..511 (2 c/thread)
  if (blk < 512) {
    const int loe = blk * 4 + (t >> 6);                    // l*128 + o
    const int l = loe >> 7, o = loe & 127, c0 = (t & 63) * 2;
    unsigned int pk;
    if (fp32m) {
      const float* Wf = (const float*)Wv;
      pk = packbf(Wf[(size_t)c0 * 2048 + l * 128 + o],
                  Wf[(size_t)(c0 + 1) * 2048 + l * 128 + o]);
    } else {
      const unsigned short* Wh = (const unsigned short*)Wv;
      pk = (unsigned int)Wh[(size_t)c0 * 2048 + l * 128 + o]
         | ((unsigned int)Wh[(size_t)(c0 + 1) * 2048 + l * 128 + o] << 16);
    }
    ((unsigned int*)((char*)ws + WT_OFF))[(size_t)loe * 64 + (c0 >> 1)] = pk;
  }
  if (fp32m) {
    const float* xf = (const float*)xin;
#pragma unroll
    for (int it = 0; it < 8; ++it) {
      int i = t + it * 256;                                // [0,2048)
      int s = i >> 1, hf = i & 1;
      float4 v = *(const float4*)(xf + ((size_t)b * 1024 + s) * 128 + cq * 8 + hf * 4);
      int p = s & 31, j = s >> 5;
      *(uint2*)&xs[p * 264 + j * 8 + hf * 4] = make_uint2(packbf(v.x, v.y), packbf(v.z, v.w));
    }
  } else {
    const unsigned short* xh = (const unsigned short*)xin;
#pragma unroll
    for (int it = 0; it < 4; ++it) {
      int s = t + it * 256;                                // [0,1024)
      uint4 v = *(const uint4*)(xh + ((size_t)b * 1024 + s) * 128 + cq * 8);
      int p = s & 31, j = s >> 5;
      *(uint4*)&xs[p * 264 + j * 8] = v;
    }
  }
  __syncthreads();
  {   // phase 1: one 32-pt real DFT per thread. thread = (j, c).
    DEF_TRIG;
    const int j = t >> 3, c = t & 7, rb = j * 8 + c;
    float x0  = us2f((unsigned int)xs[rb]);
    float x16 = us2f((unsigned int)xs[16 * 264 + rb]);
    float sp[16], dm[16];
#pragma unroll
    for (int p = 1; p <= 15; ++p) {
      float a  = us2f((unsigned int)xs[p * 264 + rb]);
      float bq = us2f((unsigned int)xs[(32 - p) * 264 + rb]);
      sp[p] = a + bq; dm[p] = a - bq;
    }
#pragma unroll
    for (int mi = 0; mi < 16; ++mi) {
      float re = x0 + ((mi & 1) ? -x16 : x16);
      float im = 0.f;
#pragma unroll
      for (int p = 1; p <= 15; ++p) {
        re += sp[p] * CT[(mi * p) & 31];
        im -= dm[p] * ST[(mi * p) & 31];
      }
      fsp2[(mi * 16 + 2 * c + 0) * 36 + j] = f2us(re);
      fsp2[(mi * 16 + 2 * c + 1) * 36 + j] = f2us(im);
    }
  }
  __syncthreads();                                         // xs dead; fsp2 ready
  ((uint4*)xs)[t] = at0;                                   // stage atab into xs
  ((uint4*)xs)[t + 256] = at1;
  if (t < 32) ((uint4*)xs)[512 + t] = at2;
  __syncthreads();
  {   // phase 2: MFMA quadrature. wave wv -> m = wv*4..wv*4+3.
    const int wv = t >> 6, lane = t & 63;
    const int n = lane & 15, quad = lane >> 4;
    const unsigned short* atab = (const unsigned short*)xs;
#pragma unroll
    for (int mi4 = 0; mi4 < 4; ++mi4) {
      const int mi = wv * 4 + mi4;
      const int base = mi * 16 - (mi * (mi - 1)) / 2;
      // A[row=l-slot=n][k=j]; rows beyond 16-mi are junk -> discarded D rows.
      short8 A = *(const short8*)&atab[(base + n) * 32 + quad * 8];
      short8 Bv = *(const short8*)&fsp2[(mi * 16 + n) * 36 + quad * 8];
      f32x4 d = {0.f, 0.f, 0.f, 0.f};
      d = MFMA16(A, Bv, d);
      // D row=quad*4+reg=l-slot, col=n (n even: re of c=n/2; odd: im).
      // split-plane store: partner lane n^2 holds the next channel, same ri.
#pragma unroll
      for (int reg = 0; reg < 4; ++reg) {
        float other = __shfl_xor(d[reg], 2, 64);
        int slot = quad * 4 + reg;
        int nm = n & 3;
        if (nm <= 1 && slot < 16 - mi) {
          unsigned int* plane = ws + (nm ? PIM_U : 0u);
          plane[((size_t)b * NPAIR + base + slot) * 64 + cq * 4 + (n >> 2)] =
              packbf(d[reg], other);
        }
      }
    }
  }
}

// ---------------------------------------------------------------------------
// K2: blk=(b, oq, jh), 512 blocks x 256 thr. MFMA channel-GEMM (wave wv =
// degrees wv*4..+3; A-frags raw b128 from split planes) -> chs[ol][pair]
// LDS, then Legendre synthesis + iDFT + bias for 16 j rows (2 per thread).
// ---------------------------------------------------------------------------
__global__ __launch_bounds__(256, 4) void k_cbf(const unsigned int* __restrict__ ws,
                                                char* __restrict__ outbuf,
                                                const void* __restrict__ biasv,
                                                const void* __restrict__ xin) {
  const int fp32m = detect_fp32(xin);
  __shared__ __align__(16) char smem[SMEM_BYTES];
  unsigned int* chs = (unsigned int*)smem;                 // [32][PADC] re|im bf16
  float* stb = (float*)(smem + 32 * PADC * 4);             // [16][PADC]
  const unsigned short* wt = (const unsigned short*)((const char*)ws + WT_OFF);
  const int blk = blockIdx.x, t = threadIdx.x;
  const int b = blk >> 3, oq = (blk >> 1) & 3, jh = blk & 1;
  // stage stb rows jh*16..+15 (35 float4 per row)
  for (int i = t; i < 16 * 35; i += 256) {
    int row = i / 35, w = i % 35;
    ((float4*)stb)[row * 35 + w] = ((const float4*)g_stab)[(jh * 16 + row) * 35 + w];
  }
  {   // ---- MFMA prologue: wave wv covers degrees lw = wv*4 .. wv*4+3.
    const int wv = t >> 6, lane = t & 63;
    const int col = lane & 15, quad = lane >> 4;
    const int s = col;
#pragma unroll
    for (int li = 0; li < 4; ++li) {
      const int lw = wv * 4 + li;
      const int av = (s <= lw);
      const int pv = av ? (s * 16 - (s * (s - 1)) / 2 + (lw - s)) : 0;
      short8 Bf[2][4];
#pragma unroll
      for (int nt = 0; nt < 2; ++nt) {
        const unsigned short* wp = wt + ((size_t)lw * 128 + oq * 32 + nt * 16 + col) * 128;
#pragma unroll
        for (int kc = 0; kc < 4; ++kc)
          Bf[nt][kc] = *(const short8*)(wp + kc * 32 + quad * 8);
      }
      f32x4 aR0 = {0.f, 0.f, 0.f, 0.f}, aI0 = aR0, aR1 = aR0, aI1 = aR0;
#pragma unroll
      for (int kc = 0; kc < 4; ++kc) {
        uint4 ur = {0u, 0u, 0u, 0u}, ui = ur;
        if (av) {
          size_t base = ((size_t)b * NPAIR + pv) * 64 + kc * 16 + quad * 4;
          ur = *(const uint4*)&ws[base];
          ui = *(const uint4*)&ws[PIM_U + base];
        }
        short8 Ar = *(short8*)&ur, Ai = *(short8*)&ui;
        aR0 = MFMA16(Ar, Bf[0][kc], aR0);
        aI0 = MFMA16(Ai, Bf[0][kc], aI0);
        aR1 = MFMA16(Ar, Bf[1][kc], aR1);
        aI1 = MFMA16(Ai, Bf[1][kc], aI1);
      }
#pragma unroll
      for (int reg = 0; reg < 4; ++reg) {
        int slot = quad * 4 + reg;
        if (slot <= lw) {
          int pp_ = slot * 16 - (slot * (slot - 1)) / 2 + (lw - slot);
          chs[col * PADC + pp_] = packbf(aR0[reg], aI0[reg]);
          chs[(16 + col) * PADC + pp_] = packbf(aR1[reg], aI1[reg]);
        }
      }
    }
  }
  const int j8 = t >> 5, ol = t & 31;
  const int o = oq * 32 + ol;
  const float bv = fp32m ? ((const float*)biasv)[o]
                         : us2f((unsigned int)((const unsigned short*)biasv)[o]);
  __syncthreads();
  DEF_TRIG;
#pragma unroll 1
  for (int jj = 0; jj < 2; ++jj) {
    const int jl = j8 * 2 + jj, j = jh * 16 + jl;
    float Gr[16], Gi[16];
#pragma unroll
    for (int mm = 0; mm < 16; ++mm) { Gr[mm] = 0.f; Gi[mm] = 0.f; }
    {
      float4 s4 = {0.f, 0.f, 0.f, 0.f};
      uint4  c4 = {0u, 0u, 0u, 0u};
      int pair = 0;
#pragma unroll
      for (int mm = 0; mm < 16; ++mm) {
#pragma unroll
        for (int l = mm; l < 16; ++l) {
          if ((pair & 3) == 0) {                           // folds: pair is unroll-const
            s4 = *(const float4*)&stb[jl * PADC + pair];
            c4 = *(const uint4*)&chs[ol * PADC + pair];
          }
          const int r = pair & 3;
          const float        s  = (r == 0) ? s4.x : (r == 1) ? s4.y : (r == 2) ? s4.z : s4.w;
          const unsigned int cv = (r == 0) ? c4.x : (r == 1) ? c4.y : (r == 2) ? c4.z : c4.w;
          Gr[mm] += s * lo_f(cv);
          Gi[mm] += s * hi_f(cv);
          ++pair;
        }
      }
    }
#pragma unroll
    for (int pp = 0; pp <= 16; ++pp) {
      float A = 0.f, Bv = 0.f;
#pragma unroll
      for (int mm = 0; mm < 16; ++mm) {
        A  += Gr[mm] * CT[(mm * pp) & 31];
        Bv += Gi[mm] * ST[(mm * pp) & 31];
      }
      const int p2 = (32 - pp) & 31;
      size_t e1 = (size_t)b * 131072 + (size_t)(j * 32 + pp) * 128 + o;
      size_t e2 = (size_t)b * 131072 + (size_t)(j * 32 + p2) * 128 + o;
      if (fp32m) {
        *(float*)(outbuf + e1 * 4) = bv + A - Bv;
        *(float*)(outbuf + e2 * 4) = bv + A + Bv;
      } else {
        *(unsigned short*)(outbuf + e1 * 2) = f2us(bv + A - Bv);
        *(unsigned short*)(outbuf + e2 * 2) = f2us(bv + A + Bv);
      }
    }
  }
}

// ---------------------------------------------------------------------------
extern "C" void kernel_launch(void* const* d_in, const int* in_sizes, int n_in,
                              void* d_out, int out_size, void* d_ws, size_t ws_size,
                              hipStream_t stream) {
  const void* xin  = d_in[0];   // (64,32,32,128) fp32 or bf16 (auto-detected)
  const void* W    = d_in[1];   // (128,16,128)
  const void* bias = d_in[2];   // (128)
  char* out = (char*)d_out;
  unsigned int* ws = (unsigned int*)d_ws;  // re@0, im@4MB, Wt@8MB

  hipLaunchKernelGGL(k_init, dim3(NPAIR), dim3(32),  0, stream);
  hipLaunchKernelGGL(k_fwd,  dim3(1024),  dim3(256), 0, stream, xin, ws, W);
  hipLaunchKernelGGL(k_cbf,  dim3(512),   dim3(256), 0, stream, ws, out, bias, xin);
}

// Round 7
// 111.215 us; speedup vs baseline: 2.2150x; 2.2150x over previous
//
#include <hip/hip_runtime.h>
#include <hip/hip_bf16.h>
#include <math.h>

// SphConv: B=64, n=32, C_in=C_out=128, L=16, (l,m) pairs l>=m: 136.
// Three plain launches (cooperative launch breaks harness graph capture):
//   k_init: tables (memoized via g_tab_ready)
//   k_fwd : FFT(phi) + MFMA Legendre analysis -> coef split re/im planes
//           in d_ws; W->Wt[l][o][c] bf16 transpose tail on blks<512
//   k_cb  : blk=(b,oq) x 1024 thr (R4 shape — R6's 512x256 jh-split halved
//           occupancy, doubled GEMM work, serialized 4 degrees/wave ->
//           157 us latency-bound disaster, reverted): wave = one degree,
//           A-frags raw b128 from split planes (no unpack — the one R6
//           delta that survives), -> chs LDS [ol][pair], then synthesis +
//           iDFT + bias, one j per thread.
// bf16 pack points identical to R4 -> identical numerics.

#define NPAIR 136
#define PADC 140            // pair-minor row stride (136 + 4 pad)
#define PIM_U (1u << 20)    // im-plane offset in uints (4 MB)
#define WT_OFF (8u << 20)   // byte offset of Wt[l][o][c] bf16 in d_ws
#define SMEM_A 35328        // phase A: 16896 (xs) + 18432 (fsp2)

typedef __attribute__((ext_vector_type(8))) short short8;
typedef __attribute__((ext_vector_type(4))) float f32x4;
#define MFMA16(A, B, C) __builtin_amdgcn_mfma_f32_16x16x32_bf16(A, B, C, 0, 0, 0)

static __device__ __forceinline__ float us2f(unsigned int u) {
  union { unsigned int i; float f; } v; v.i = u << 16; return v.f;
}
static __device__ __forceinline__ unsigned short f2us(float f) {
  __hip_bfloat16 h = __float2bfloat16(f);
  return *(unsigned short*)&h;
}
static __device__ __forceinline__ float lo_f(unsigned int pk) {
  union { unsigned int i; float f; } v; v.i = pk << 16; return v.f;
}
static __device__ __forceinline__ float hi_f(unsigned int pk) {
  union { unsigned int i; float f; } v; v.i = pk & 0xffff0000u; return v.f;
}
static __device__ __forceinline__ unsigned int packbf(float a, float b) {
  return (unsigned int)f2us(a) | ((unsigned int)f2us(b) << 16);
}

__device__ __align__(16) unsigned short g_atab_h[NPAIR * 32]; // bf16 Q*wj
__device__ __align__(16) float          g_stab[32 * PADC];    // fp32 Q*scale*(m?2:1), [j][pair]
__device__ int g_tab_ready;                                   // tables memoized across runs

static __device__ __forceinline__ int detect_fp32(const void* xin) {
  const unsigned short* u = (const unsigned short*)xin;
  int lane = threadIdx.x & 63;
  int big = 0;
#pragma unroll
  for (int q = 0; q < 4; ++q) {
    float v = us2f((unsigned int)u[lane * 8 + q * 2]);
    if (!(fabsf(v) <= 1e3f)) big = 1;
  }
  unsigned long long mask = __ballot(big);
  return (__popcll(mask) >= 16) ? 1 : 0;
}

// 32-pt DFT trig tables, cos/sin(2*pi*k/32) — compile-time indices only
#define DEF_TRIG \
  constexpr float CT[32] = { \
    1.0f, 0.98078528f, 0.92387953f, 0.83146961f, 0.70710678f, 0.55557023f, \
    0.38268343f, 0.19509032f, 0.0f, -0.19509032f, -0.38268343f, -0.55557023f, \
    -0.70710678f, -0.83146961f, -0.92387953f, -0.98078528f, -1.0f, \
    -0.98078528f, -0.92387953f, -0.83146961f, -0.70710678f, -0.55557023f, \
    -0.38268343f, -0.19509032f, 0.0f, 0.19509032f, 0.38268343f, 0.55557023f, \
    0.70710678f, 0.83146961f, 0.92387953f, 0.98078528f }; \
  constexpr float ST[32] = { \
    0.0f, 0.19509032f, 0.38268343f, 0.55557023f, 0.70710678f, 0.83146961f, \
    0.92387953f, 0.98078528f, 1.0f, 0.98078528f, 0.92387953f, 0.83146961f, \
    0.70710678f, 0.55557023f, 0.38268343f, 0.19509032f, 0.0f, \
    -0.19509032f, -0.38268343f, -0.55557023f, -0.70710678f, -0.83146961f, \
    -0.92387953f, -0.98078528f, -1.0f, -0.98078528f, -0.92387953f, \
    -0.83146961f, -0.70710678f, -0.55557023f, -0.38268343f, -0.19509032f }

// ---------------------------------------------------------------------------
// Table compute for one (pair, j) — fp64, input-independent.
// ---------------------------------------------------------------------------
static __device__ void tab_compute(int pair, int j) {
  int m = 0;
#pragma unroll
  for (int mm = 1; mm < 16; ++mm) {
    int off = mm * 16 - (mm * (mm - 1)) / 2;
    if (off <= pair) m = mm;
  }
  const int l = m + (pair - (m * 16 - (m * (m - 1)) / 2));
  double theta = M_PI * (j + 0.5) / 32.0;
  double x = cos(theta), sx = sin(theta);
  double wj = sx * (M_PI / 32.0) * (2.0 * M_PI / 32.0);
  double pmm = 1.0;
  for (int k = 1; k <= m; ++k) pmm *= -(2.0 * k - 1.0) * sx;
  double p = pmm, pl1 = 0.0, pl2 = 0.0;
  for (int ll = m; ll <= l; ++ll) {
    if (ll == m)          p = pmm;
    else if (ll == m + 1) p = (2.0 * m + 1.0) * x * pmm;
    else                  p = ((2.0 * ll - 1.0) * x * pl1 - (double)(ll + m - 1) * pl2) / (double)(ll - m);
    pl2 = pl1; pl1 = p;
  }
  double r = 1.0;
  for (int k = l - m + 1; k <= l + m; ++k) r *= (double)k;   // (l+m)!/(l-m)!
  double Nlm = sqrt((2.0 * l + 1.0) / (4.0 * M_PI) / r);
  g_atab_h[pair * 32 + j] = f2us((float)(Nlm * p * wj));
  g_stab[j * PADC + pair] = (float)(Nlm * p * (2.0 * M_PI * sqrt(4.0 * M_PI / (2.0 * l + 1.0)))
                                    * (m ? 2.0 : 1.0));
}

// ---------------------------------------------------------------------------
// K0: tables. One block per (l,m) pair x 32 j. Memoized via g_tab_ready.
// ---------------------------------------------------------------------------
__global__ void k_init() {
  if (g_tab_ready) return;
  tab_compute(blockIdx.x, threadIdx.x);
  if (blockIdx.x == NPAIR - 1 && threadIdx.x == 31) g_tab_ready = 1;
}

// ---------------------------------------------------------------------------
// K1: FFT(phi) + MFMA Legendre analysis. blk=(b XCD-swizzled, cq).
// Phase 1: one (j,c) DFT per thread -> fsp2[m][n=2c+ri][j] u16.
// Phase 2: MFMA per m (wave wv handles m=wv*4..+3); D -> coef split planes
// plane_re[b][pair][w] / plane_im (+PIM_U), word w = channels {2w, 2w+1}.
// Tail (blk<512): W -> Wt[l][o][c] bf16 transpose (per-call, W varies).
// ---------------------------------------------------------------------------
__global__ __launch_bounds__(256) void k_fwd(const void* __restrict__ xin,
                                             unsigned int* __restrict__ ws,
                                             const void* __restrict__ Wv) {
  const int fp32m = detect_fp32(xin);
  __shared__ __align__(16) char smem[SMEM_A];
  unsigned short* xs   = (unsigned short*)smem;            // [p][j*8+c]; atab after ph1
  unsigned short* fsp2 = xs + 32 * 264;                    // [m][n][j] 18 KB
  const int blk = blockIdx.x;
  const int b = (blk & 7) | (((blk >> 7) & 7) << 3);       // same-b -> same XCD
  const int cq = (blk >> 3) & 15;                          // 8-channel group
  const int t = threadIdx.x;
  // prefetch atab (544 uint4) into registers — latency hides under phase 1
  uint4 at0 = ((const uint4*)g_atab_h)[t];
  uint4 at1 = ((const uint4*)g_atab_h)[t + 256];
  uint4 at2;
  if (t < 32) at2 = ((const uint4*)g_atab_h)[512 + t];
  // W -> Wt transpose tail work, distributed over blocks 0..511 (2 c/thread)
  if (blk < 512) {
    const int loe = blk * 4 + (t >> 6);                    // l*128 + o
    const int l = loe >> 7, o = loe & 127, c0 = (t & 63) * 2;
    unsigned int pk;
    if (fp32m) {
      const float* Wf = (const float*)Wv;
      pk = packbf(Wf[(size_t)c0 * 2048 + l * 128 + o],
                  Wf[(size_t)(c0 + 1) * 2048 + l * 128 + o]);
    } else {
      const unsigned short* Wh = (const unsigned short*)Wv;
      pk = (unsigned int)Wh[(size_t)c0 * 2048 + l * 128 + o]
         | ((unsigned int)Wh[(size_t)(c0 + 1) * 2048 + l * 128 + o] << 16);
    }
    ((unsigned int*)((char*)ws + WT_OFF))[(size_t)loe * 64 + (c0 >> 1)] = pk;
  }
  if (fp32m) {
    const float* xf = (const float*)xin;
#pragma unroll
    for (int it = 0; it < 8; ++it) {
      int i = t + it * 256;                                // [0,2048)
      int s = i >> 1, hf = i & 1;
      float4 v = *(const float4*)(xf + ((size_t)b * 1024 + s) * 128 + cq * 8 + hf * 4);
      int p = s & 31, j = s >> 5;
      *(uint2*)&xs[p * 264 + j * 8 + hf * 4] = make_uint2(packbf(v.x, v.y), packbf(v.z, v.w));
    }
  } else {
    const unsigned short* xh = (const unsigned short*)xin;
#pragma unroll
    for (int it = 0; it < 4; ++it) {
      int s = t + it * 256;                                // [0,1024)
      uint4 v = *(const uint4*)(xh + ((size_t)b * 1024 + s) * 128 + cq * 8);
      int p = s & 31, j = s >> 5;
      *(uint4*)&xs[p * 264 + j * 8] = v;
    }
  }
  __syncthreads();
  {   // phase 1: one 32-pt real DFT per thread. thread = (j, c).
    DEF_TRIG;
    const int j = t >> 3, c = t & 7, rb = j * 8 + c;
    float x0  = us2f((unsigned int)xs[rb]);
    float x16 = us2f((unsigned int)xs[16 * 264 + rb]);
    float sp[16], dm[16];
#pragma unroll
    for (int p = 1; p <= 15; ++p) {
      float a  = us2f((unsigned int)xs[p * 264 + rb]);
      float bq = us2f((unsigned int)xs[(32 - p) * 264 + rb]);
      sp[p] = a + bq; dm[p] = a - bq;
    }
#pragma unroll
    for (int mi = 0; mi < 16; ++mi) {
      float re = x0 + ((mi & 1) ? -x16 : x16);
      float im = 0.f;
#pragma unroll
      for (int p = 1; p <= 15; ++p) {
        re += sp[p] * CT[(mi * p) & 31];
        im -= dm[p] * ST[(mi * p) & 31];
      }
      fsp2[(mi * 16 + 2 * c + 0) * 36 + j] = f2us(re);
      fsp2[(mi * 16 + 2 * c + 1) * 36 + j] = f2us(im);
    }
  }
  __syncthreads();                                         // xs dead; fsp2 ready
  ((uint4*)xs)[t] = at0;                                   // stage atab into xs
  ((uint4*)xs)[t + 256] = at1;
  if (t < 32) ((uint4*)xs)[512 + t] = at2;
  __syncthreads();
  {   // phase 2: MFMA quadrature. wave wv -> m = wv*4..wv*4+3.
    const int wv = t >> 6, lane = t & 63;
    const int n = lane & 15, quad = lane >> 4;
    const unsigned short* atab = (const unsigned short*)xs;
#pragma unroll
    for (int mi4 = 0; mi4 < 4; ++mi4) {
      const int mi = wv * 4 + mi4;
      const int base = mi * 16 - (mi * (mi - 1)) / 2;
      // A[row=l-slot=n][k=j]; rows beyond 16-mi are junk -> discarded D rows.
      short8 A = *(const short8*)&atab[(base + n) * 32 + quad * 8];
      short8 Bv = *(const short8*)&fsp2[(mi * 16 + n) * 36 + quad * 8];
      f32x4 d = {0.f, 0.f, 0.f, 0.f};
      d = MFMA16(A, Bv, d);
      // D row=quad*4+reg=l-slot, col=n (n even: re of c=n/2; odd: im).
      // split-plane store: partner lane n^2 holds the next channel, same ri.
#pragma unroll
      for (int reg = 0; reg < 4; ++reg) {
        float other = __shfl_xor(d[reg], 2, 64);
        int slot = quad * 4 + reg;
        int nm = n & 3;
        if (nm <= 1 && slot < 16 - mi) {
          unsigned int* plane = ws + (nm ? PIM_U : 0u);
          plane[((size_t)b * NPAIR + base + slot) * 64 + cq * 4 + (n >> 2)] =
              packbf(d[reg], other);
        }
      }
    }
  }
}

// ---------------------------------------------------------------------------
// K2: blk=(b, oq), 256 blocks x 1024 thr (16 waves, 4 waves/SIMD). MFMA
// channel-GEMM: wave = one degree lw; A-frags raw b128 from split planes
// (no unpack); B-frags coalesced b128 from Wt. D -> chs[ol][pair] LDS.
// Then Legendre synthesis + iDFT + bias, one j per thread.
// ---------------------------------------------------------------------------
__global__ __launch_bounds__(1024, 4) void k_cb(const unsigned int* __restrict__ ws,
                                                char* __restrict__ outbuf,
                                                const void* __restrict__ biasv,
                                                const void* __restrict__ xin) {
  const int fp32m = detect_fp32(xin);
  __shared__ __align__(16) unsigned int chs[32 * PADC];    // [ol][pair] re|im bf16
  __shared__ __align__(16) float        stb[32 * PADC];    // [j][pair]
  const unsigned short* wt = (const unsigned short*)((const char*)ws + WT_OFF);
  const int b = blockIdx.x >> 2, oq = blockIdx.x & 3;
  const int t = threadIdx.x;
  // stage stb (independent of MFMA phase)
  for (int i = t; i < 32 * PADC / 4; i += 1024)
    ((float4*)stb)[i] = ((const float4*)g_stab)[i];
  {   // ---- MFMA phase: wave = degree lw.
    const int lw = t >> 6, lane = t & 63;
    const int col = lane & 15, quad = lane >> 4;
    const int s = col;
    const int av = (s <= lw);
    const int pv = av ? (s * 16 - (s * (s - 1)) / 2 + (lw - s)) : 0;
    // B fragments: 2 nt x 4 kc, coalesced b128 from Wt[lw][o][c]
    short8 Bf[2][4];
#pragma unroll
    for (int nt = 0; nt < 2; ++nt) {
      const unsigned short* wp = wt + ((size_t)lw * 128 + oq * 32 + nt * 16 + col) * 128;
#pragma unroll
      for (int kc = 0; kc < 4; ++kc)
        Bf[nt][kc] = *(const short8*)(wp + kc * 32 + quad * 8);
    }
    f32x4 aR0 = {0.f, 0.f, 0.f, 0.f}, aI0 = aR0, aR1 = aR0, aI1 = aR0;
#pragma unroll
    for (int kc = 0; kc < 4; ++kc) {
      uint4 ur = {0u, 0u, 0u, 0u}, ui = ur;
      if (av) {
        size_t base = ((size_t)b * NPAIR + pv) * 64 + kc * 16 + quad * 4;
        ur = *(const uint4*)&ws[base];
        ui = *(const uint4*)&ws[PIM_U + base];
      }
      short8 Ar = *(short8*)&ur, Ai = *(short8*)&ui;
      aR0 = MFMA16(Ar, Bf[0][kc], aR0);
      aI0 = MFMA16(Ai, Bf[0][kc], aI0);
      aR1 = MFMA16(Ar, Bf[1][kc], aR1);
      aI1 = MFMA16(Ai, Bf[1][kc], aI1);
    }
    // write chat directly into chs[ol][pair]; D row=quad*4+reg=slot.
#pragma unroll
    for (int reg = 0; reg < 4; ++reg) {
      int slot = quad * 4 + reg;
      if (slot <= lw) {
        int pp_ = slot * 16 - (slot * (slot - 1)) / 2 + (lw - slot);
        chs[col * PADC + pp_] = packbf(aR0[reg], aI0[reg]);
        chs[(16 + col) * PADC + pp_] = packbf(aR1[reg], aI1[reg]);
      }
    }
  }
  const int j = t >> 5, ol = t & 31;
  const int o = oq * 32 + ol;
  const float bv = fp32m ? ((const float*)biasv)[o]
                         : us2f((unsigned int)((const unsigned short*)biasv)[o]);
  __syncthreads();

  float Gr[16], Gi[16];
#pragma unroll
  for (int mm = 0; mm < 16; ++mm) { Gr[mm] = 0.f; Gi[mm] = 0.f; }
  {
    float4 s4 = {0.f, 0.f, 0.f, 0.f};
    uint4  c4 = {0u, 0u, 0u, 0u};
    int pair = 0;
#pragma unroll
    for (int mm = 0; mm < 16; ++mm) {
#pragma unroll
      for (int l = mm; l < 16; ++l) {
        if ((pair & 3) == 0) {                             // folds: pair is unroll-const
          s4 = *(const float4*)&stb[j * PADC + pair];
          c4 = *(const uint4*)&chs[ol * PADC + pair];
        }
        const int r = pair & 3;
        const float        s  = (r == 0) ? s4.x : (r == 1) ? s4.y : (r == 2) ? s4.z : s4.w;
        const unsigned int cv = (r == 0) ? c4.x : (r == 1) ? c4.y : (r == 2) ? c4.z : c4.w;
        Gr[mm] += s * lo_f(cv);
        Gi[mm] += s * hi_f(cv);
        ++pair;
      }
    }
  }
  DEF_TRIG;
#pragma unroll
  for (int pp = 0; pp <= 16; ++pp) {
    float A = 0.f, Bv = 0.f;
#pragma unroll
    for (int mm = 0; mm < 16; ++mm) {
      A  += Gr[mm] * CT[(mm * pp) & 31];
      Bv += Gi[mm] * ST[(mm * pp) & 31];
    }
    const int p2 = (32 - pp) & 31;
    size_t e1 = (size_t)b * 131072 + (size_t)(j * 32 + pp) * 128 + o;
    size_t e2 = (size_t)b * 131072 + (size_t)(j * 32 + p2) * 128 + o;
    if (fp32m) {
      *(float*)(outbuf + e1 * 4) = bv + A - Bv;
      *(float*)(outbuf + e2 * 4) = bv + A + Bv;
    } else {
      *(unsigned short*)(outbuf + e1 * 2) = f2us(bv + A - Bv);
      *(unsigned short*)(outbuf + e2 * 2) = f2us(bv + A + Bv);
    }
  }
}

// ---------------------------------------------------------------------------
extern "C" void kernel_launch(void* const* d_in, const int* in_sizes, int n_in,
                              void* d_out, int out_size, void* d_ws, size_t ws_size,
                              hipStream_t stream) {
  const void* xin  = d_in[0];   // (64,32,32,128) fp32 or bf16 (auto-detected)
  const void* W    = d_in[1];   // (128,16,128)
  const void* bias = d_in[2];   // (128)
  char* out = (char*)d_out;
  unsigned int* ws = (unsigned int*)d_ws;  // re@0, im@4MB, Wt@8MB

  hipLaunchKernelGGL(k_init, dim3(NPAIR), dim3(32),   0, stream);
  hipLaunchKernelGGL(k_fwd,  dim3(1024),  dim3(256),  0, stream, xin, ws, W);
  hipLaunchKernelGGL(k_cb,   dim3(256),   dim3(1024), 0, stream, ws, out, bias, xin);
}

// Round 8
// 110.653 us; speedup vs baseline: 2.2262x; 1.0051x over previous
//
#include <hip/hip_runtime.h>
#include <hip/hip_bf16.h>
#include <math.h>

// SphConv: B=64, n=32, C_in=C_out=128, L=16, (l,m) pairs l>=m: 136.
// TWO plain launches (cooperative launch breaks harness graph capture; R5):
//   k_fwd : FFT(phi) + MFMA Legendre analysis -> coef split re/im planes
//           in d_ws; W->Wt[l][o][c] bf16 transpose tail on blks<512.
//           Tables self-initialize on first call (g_tab_ready memoization;
//           identical fp64 math -> identical bf16 values; block 0 persists
//           g_atab_h/g_stab for steady-state prefetch path) — k_init launch
//           eliminated (was ~2us dispatch+drain per iteration).
//   k_cb  : blk=(b,oq) x 1024 thr: wave = one degree, A-frags raw b128
//           from split planes, B-frags b128 from Wt -> chs LDS [ol][pair],
//           then Legendre synthesis + iDFT + bias, one j per thread.
// bf16 pack points identical to R4/R7 -> identical numerics.

#define NPAIR 136
#define PADC 140            // pair-minor row stride (136 + 4 pad)
#define PIM_U (1u << 20)    // im-plane offset in uints (4 MB)
#define WT_OFF (8u << 20)   // byte offset of Wt[l][o][c] bf16 in d_ws
#define SMEM_A 35328        // phase A: 16896 (xs) + 18432 (fsp2)

typedef __attribute__((ext_vector_type(8))) short short8;
typedef __attribute__((ext_vector_type(4))) float f32x4;
#define MFMA16(A, B, C) __builtin_amdgcn_mfma_f32_16x16x32_bf16(A, B, C, 0, 0, 0)

static __device__ __forceinline__ float us2f(unsigned int u) {
  union { unsigned int i; float f; } v; v.i = u << 16; return v.f;
}
static __device__ __forceinline__ unsigned short f2us(float f) {
  __hip_bfloat16 h = __float2bfloat16(f);
  return *(unsigned short*)&h;
}
static __device__ __forceinline__ float lo_f(unsigned int pk) {
  union { unsigned int i; float f; } v; v.i = pk << 16; return v.f;
}
static __device__ __forceinline__ float hi_f(unsigned int pk) {
  union { unsigned int i; float f; } v; v.i = pk & 0xffff0000u; return v.f;
}
static __device__ __forceinline__ unsigned int packbf(float a, float b) {
  return (unsigned int)f2us(a) | ((unsigned int)f2us(b) << 16);
}

__device__ __align__(16) unsigned short g_atab_h[NPAIR * 32]; // bf16 Q*wj
__device__ __align__(16) float          g_stab[32 * PADC];    // fp32 Q*scale*(m?2:1), [j][pair]
__device__ int g_tab_ready;                                   // tables memoized across runs

static __device__ __forceinline__ int detect_fp32(const void* xin) {
  const unsigned short* u = (const unsigned short*)xin;
  int lane = threadIdx.x & 63;
  int big = 0;
#pragma unroll
  for (int q = 0; q < 4; ++q) {
    float v = us2f((unsigned int)u[lane * 8 + q * 2]);
    if (!(fabsf(v) <= 1e3f)) big = 1;
  }
  unsigned long long mask = __ballot(big);
  return (__popcll(mask) >= 16) ? 1 : 0;
}

// 32-pt DFT trig tables, cos/sin(2*pi*k/32) — compile-time indices only
#define DEF_TRIG \
  constexpr float CT[32] = { \
    1.0f, 0.98078528f, 0.92387953f, 0.83146961f, 0.70710678f, 0.55557023f, \
    0.38268343f, 0.19509032f, 0.0f, -0.19509032f, -0.38268343f, -0.55557023f, \
    -0.70710678f, -0.83146961f, -0.92387953f, -0.98078528f, -1.0f, \
    -0.98078528f, -0.92387953f, -0.83146961f, -0.70710678f, -0.55557023f, \
    -0.38268343f, -0.19509032f, 0.0f, 0.19509032f, 0.38268343f, 0.55557023f, \
    0.70710678f, 0.83146961f, 0.92387953f, 0.98078528f }; \
  constexpr float ST[32] = { \
    0.0f, 0.19509032f, 0.38268343f, 0.55557023f, 0.70710678f, 0.83146961f, \
    0.92387953f, 0.98078528f, 1.0f, 0.98078528f, 0.92387953f, 0.83146961f, \
    0.70710678f, 0.55557023f, 0.38268343f, 0.19509032f, 0.0f, \
    -0.19509032f, -0.38268343f, -0.55557023f, -0.70710678f, -0.83146961f, \
    -0.92387953f, -0.98078528f, -1.0f, -0.98078528f, -0.92387953f, \
    -0.83146961f, -0.70710678f, -0.55557023f, -0.38268343f, -0.19509032f }

// ---------------------------------------------------------------------------
// Table core for one (pair, j) — fp64, input-independent. Returns the
// atab value (Nlm*P*wj) and stab value (Nlm*P*scale*(m?2:1)).
// ---------------------------------------------------------------------------
static __device__ void tab_core(int pair, int j, float* aval, float* sval) {
  int m = 0;
#pragma unroll
  for (int mm = 1; mm < 16; ++mm) {
    int off = mm * 16 - (mm * (mm - 1)) / 2;
    if (off <= pair) m = mm;
  }
  const int l = m + (pair - (m * 16 - (m * (m - 1)) / 2));
  double theta = M_PI * (j + 0.5) / 32.0;
  double x = cos(theta), sx = sin(theta);
  double wj = sx * (M_PI / 32.0) * (2.0 * M_PI / 32.0);
  double pmm = 1.0;
  for (int k = 1; k <= m; ++k) pmm *= -(2.0 * k - 1.0) * sx;
  double p = pmm, pl1 = 0.0, pl2 = 0.0;
  for (int ll = m; ll <= l; ++ll) {
    if (ll == m)          p = pmm;
    else if (ll == m + 1) p = (2.0 * m + 1.0) * x * pmm;
    else                  p = ((2.0 * ll - 1.0) * x * pl1 - (double)(ll + m - 1) * pl2) / (double)(ll - m);
    pl2 = pl1; pl1 = p;
  }
  double r = 1.0;
  for (int k = l - m + 1; k <= l + m; ++k) r *= (double)k;   // (l+m)!/(l-m)!
  double Nlm = sqrt((2.0 * l + 1.0) / (4.0 * M_PI) / r);
  *aval = (float)(Nlm * p * wj);
  *sval = (float)(Nlm * p * (2.0 * M_PI * sqrt(4.0 * M_PI / (2.0 * l + 1.0)))
                  * (m ? 2.0 : 1.0));
}

// ---------------------------------------------------------------------------
// K1: FFT(phi) + MFMA Legendre analysis. blk=(b XCD-swizzled, cq).
// First call (!g_tab_ready): threads self-compute their atab prefetch
// entries (identical fp64 math -> identical bf16); block 0 persists both
// tables to global and sets the flag for steady-state runs.
// Phase 1: one (j,c) DFT per thread -> fsp2[m][n=2c+ri][j] u16.
// Phase 2: MFMA per m (wave wv handles m=wv*4..+3); D -> coef split planes
// plane_re[b][pair][w] / plane_im (+PIM_U), word w = channels {2w, 2w+1}.
// Tail (blk<512): W -> Wt[l][o][c] bf16 transpose (per-call, W varies).
// ---------------------------------------------------------------------------
__global__ __launch_bounds__(256) void k_fwd(const void* __restrict__ xin,
                                             unsigned int* __restrict__ ws,
                                             const void* __restrict__ Wv) {
  const int fp32m = detect_fp32(xin);
  __shared__ __align__(16) char smem[SMEM_A];
  unsigned short* xs   = (unsigned short*)smem;            // [p][j*8+c]; atab after ph1
  unsigned short* fsp2 = xs + 32 * 264;                    // [m][n][j] 18 KB
  const int blk = blockIdx.x;
  const int b = (blk & 7) | (((blk >> 7) & 7) << 3);       // same-b -> same XCD
  const int cq = (blk >> 3) & 15;                          // 8-channel group
  const int t = threadIdx.x;
  const int ready = g_tab_ready;
  // atab prefetch (544 uint4) into registers — latency hides under phase 1.
  // First call: self-compute the same entries (uint4 u covers pair=u/4,
  // j=(u%4)*8..+7); block 0 persists tables for future launches.
  uint4 at0, at1, at2;
  if (ready) {
    at0 = ((const uint4*)g_atab_h)[t];
    at1 = ((const uint4*)g_atab_h)[t + 256];
    if (t < 32) at2 = ((const uint4*)g_atab_h)[512 + t];
  } else {
    __align__(16) unsigned short e[8];
    const int j0 = (t & 3) * 8;
    float a, s;
#pragma unroll
    for (int r = 0; r < 8; ++r) { tab_core((t >> 2), j0 + r, &a, &s); e[r] = f2us(a); }
    at0 = *(const uint4*)e;
#pragma unroll
    for (int r = 0; r < 8; ++r) { tab_core((t >> 2) + 64, j0 + r, &a, &s); e[r] = f2us(a); }
    at1 = *(const uint4*)e;
    if (t < 32) {
#pragma unroll
      for (int r = 0; r < 8; ++r) { tab_core((t >> 2) + 128, j0 + r, &a, &s); e[r] = f2us(a); }
      at2 = *(const uint4*)e;
    }
    if (blk == 0) {
      for (int i = t; i < NPAIR * 32; i += 256) {
        tab_core(i >> 5, i & 31, &a, &s);
        g_atab_h[(i >> 5) * 32 + (i & 31)] = f2us(a);
        g_stab[(i & 31) * PADC + (i >> 5)] = s;
      }
    }
  }
  // W -> Wt transpose tail work, distributed over blocks 0..511 (2 c/thread)
  if (blk < 512) {
    const int loe = blk * 4 + (t >> 6);                    // l*128 + o
    const int l = loe >> 7, o = loe & 127, c0 = (t & 63) * 2;
    unsigned int pk;
    if (fp32m) {
      const float* Wf = (const float*)Wv;
      pk = packbf(Wf[(size_t)c0 * 2048 + l * 128 + o],
                  Wf[(size_t)(c0 + 1) * 2048 + l * 128 + o]);
    } else {
      const unsigned short* Wh = (const unsigned short*)Wv;
      pk = (unsigned int)Wh[(size_t)c0 * 2048 + l * 128 + o]
         | ((unsigned int)Wh[(size_t)(c0 + 1) * 2048 + l * 128 + o] << 16);
    }
    ((unsigned int*)((char*)ws + WT_OFF))[(size_t)loe * 64 + (c0 >> 1)] = pk;
  }
  if (fp32m) {
    const float* xf = (const float*)xin;
#pragma unroll
    for (int it = 0; it < 8; ++it) {
      int i = t + it * 256;                                // [0,2048)
      int s = i >> 1, hf = i & 1;
      float4 v = *(const float4*)(xf + ((size_t)b * 1024 + s) * 128 + cq * 8 + hf * 4);
      int p = s & 31, j = s >> 5;
      *(uint2*)&xs[p * 264 + j * 8 + hf * 4] = make_uint2(packbf(v.x, v.y), packbf(v.z, v.w));
    }
  } else {
    const unsigned short* xh = (const unsigned short*)xin;
#pragma unroll
    for (int it = 0; it < 4; ++it) {
      int s = t + it * 256;                                // [0,1024)
      uint4 v = *(const uint4*)(xh + ((size_t)b * 1024 + s) * 128 + cq * 8);
      int p = s & 31, j = s >> 5;
      *(uint4*)&xs[p * 264 + j * 8] = v;
    }
  }
  __syncthreads();
  {   // phase 1: one 32-pt real DFT per thread. thread = (j, c).
    DEF_TRIG;
    const int j = t >> 3, c = t & 7, rb = j * 8 + c;
    float x0  = us2f((unsigned int)xs[rb]);
    float x16 = us2f((unsigned int)xs[16 * 264 + rb]);
    float sp[16], dm[16];
#pragma unroll
    for (int p = 1; p <= 15; ++p) {
      float a  = us2f((unsigned int)xs[p * 264 + rb]);
      float bq = us2f((unsigned int)xs[(32 - p) * 264 + rb]);
      sp[p] = a + bq; dm[p] = a - bq;
    }
#pragma unroll
    for (int mi = 0; mi < 16; ++mi) {
      float re = x0 + ((mi & 1) ? -x16 : x16);
      float im = 0.f;
#pragma unroll
      for (int p = 1; p <= 15; ++p) {
        re += sp[p] * CT[(mi * p) & 31];
        im -= dm[p] * ST[(mi * p) & 31];
      }
      fsp2[(mi * 16 + 2 * c + 0) * 36 + j] = f2us(re);
      fsp2[(mi * 16 + 2 * c + 1) * 36 + j] = f2us(im);
    }
  }
  __syncthreads();                                         // xs dead; fsp2 ready
  ((uint4*)xs)[t] = at0;                                   // stage atab into xs
  ((uint4*)xs)[t + 256] = at1;
  if (t < 32) ((uint4*)xs)[512 + t] = at2;
  __syncthreads();
  {   // phase 2: MFMA quadrature. wave wv -> m = wv*4..wv*4+3.
    const int wv = t >> 6, lane = t & 63;
    const int n = lane & 15, quad = lane >> 4;
    const unsigned short* atab = (const unsigned short*)xs;
#pragma unroll
    for (int mi4 = 0; mi4 < 4; ++mi4) {
      const int mi = wv * 4 + mi4;
      const int base = mi * 16 - (mi * (mi - 1)) / 2;
      // A[row=l-slot=n][k=j]; rows beyond 16-mi are junk -> discarded D rows.
      short8 A = *(const short8*)&atab[(base + n) * 32 + quad * 8];
      short8 Bv = *(const short8*)&fsp2[(mi * 16 + n) * 36 + quad * 8];
      f32x4 d = {0.f, 0.f, 0.f, 0.f};
      d = MFMA16(A, Bv, d);
      // D row=quad*4+reg=l-slot, col=n (n even: re of c=n/2; odd: im).
      // split-plane store: partner lane n^2 holds the next channel, same ri.
#pragma unroll
      for (int reg = 0; reg < 4; ++reg) {
        float other = __shfl_xor(d[reg], 2, 64);
        int slot = quad * 4 + reg;
        int nm = n & 3;
        if (nm <= 1 && slot < 16 - mi) {
          unsigned int* plane = ws + (nm ? PIM_U : 0u);
          plane[((size_t)b * NPAIR + base + slot) * 64 + cq * 4 + (n >> 2)] =
              packbf(d[reg], other);
        }
      }
    }
  }
  if (!ready && blk == 0) {                                // tables persisted
    __syncthreads();
    if (t == 0) g_tab_ready = 1;
  }
}

// ---------------------------------------------------------------------------
// K2: blk=(b, oq), 256 blocks x 1024 thr (16 waves, 4 waves/SIMD). MFMA
// channel-GEMM: wave = one degree lw; A-frags raw b128 from split planes
// (no unpack); B-frags coalesced b128 from Wt. D -> chs[ol][pair] LDS.
// Then Legendre synthesis + iDFT + bias, one j per thread.
// ---------------------------------------------------------------------------
__global__ __launch_bounds__(1024, 4) void k_cb(const unsigned int* __restrict__ ws,
                                                char* __restrict__ outbuf,
                                                const void* __restrict__ biasv,
                                                const void* __restrict__ xin) {
  const int fp32m = detect_fp32(xin);
  __shared__ __align__(16) unsigned int chs[32 * PADC];    // [ol][pair] re|im bf16
  __shared__ __align__(16) float        stb[32 * PADC];    // [j][pair]
  const unsigned short* wt = (const unsigned short*)((const char*)ws + WT_OFF);
  const int b = blockIdx.x >> 2, oq = blockIdx.x & 3;
  const int t = threadIdx.x;
  // stage stb (independent of MFMA phase)
  for (int i = t; i < 32 * PADC / 4; i += 1024)
    ((float4*)stb)[i] = ((const float4*)g_stab)[i];
  {   // ---- MFMA phase: wave = degree lw.
    const int lw = t >> 6, lane = t & 63;
    const int col = lane & 15, quad = lane >> 4;
    const int s = col;
    const int av = (s <= lw);
    const int pv = av ? (s * 16 - (s * (s - 1)) / 2 + (lw - s)) : 0;
    // B fragments: 2 nt x 4 kc, coalesced b128 from Wt[lw][o][c]
    short8 Bf[2][4];
#pragma unroll
    for (int nt = 0; nt < 2; ++nt) {
      const unsigned short* wp = wt + ((size_t)lw * 128 + oq * 32 + nt * 16 + col) * 128;
#pragma unroll
      for (int kc = 0; kc < 4; ++kc)
        Bf[nt][kc] = *(const short8*)(wp + kc * 32 + quad * 8);
    }
    f32x4 aR0 = {0.f, 0.f, 0.f, 0.f}, aI0 = aR0, aR1 = aR0, aI1 = aR0;
#pragma unroll
    for (int kc = 0; kc < 4; ++kc) {
      uint4 ur = {0u, 0u, 0u, 0u}, ui = ur;
      if (av) {
        size_t base = ((size_t)b * NPAIR + pv) * 64 + kc * 16 + quad * 4;
        ur = *(const uint4*)&ws[base];
        ui = *(const uint4*)&ws[PIM_U + base];
      }
      short8 Ar = *(short8*)&ur, Ai = *(short8*)&ui;
      aR0 = MFMA16(Ar, Bf[0][kc], aR0);
      aI0 = MFMA16(Ai, Bf[0][kc], aI0);
      aR1 = MFMA16(Ar, Bf[1][kc], aR1);
      aI1 = MFMA16(Ai, Bf[1][kc], aI1);
    }
    // write chat directly into chs[ol][pair]; D row=quad*4+reg=slot.
#pragma unroll
    for (int reg = 0; reg < 4; ++reg) {
      int slot = quad * 4 + reg;
      if (slot <= lw) {
        int pp_ = slot * 16 - (slot * (slot - 1)) / 2 + (lw - slot);
        chs[col * PADC + pp_] = packbf(aR0[reg], aI0[reg]);
        chs[(16 + col) * PADC + pp_] = packbf(aR1[reg], aI1[reg]);
      }
    }
  }
  const int j = t >> 5, ol = t & 31;
  const int o = oq * 32 + ol;
  const float bv = fp32m ? ((const float*)biasv)[o]
                         : us2f((unsigned int)((const unsigned short*)biasv)[o]);
  __syncthreads();

  float Gr[16], Gi[16];
#pragma unroll
  for (int mm = 0; mm < 16; ++mm) { Gr[mm] = 0.f; Gi[mm] = 0.f; }
  {
    float4 s4 = {0.f, 0.f, 0.f, 0.f};
    uint4  c4 = {0u, 0u, 0u, 0u};
    int pair = 0;
#pragma unroll
    for (int mm = 0; mm < 16; ++mm) {
#pragma unroll
      for (int l = mm; l < 16; ++l) {
        if ((pair & 3) == 0) {                             // folds: pair is unroll-const
          s4 = *(const float4*)&stb[j * PADC + pair];
          c4 = *(const uint4*)&chs[ol * PADC + pair];
        }
        const int r = pair & 3;
        const float        s  = (r == 0) ? s4.x : (r == 1) ? s4.y : (r == 2) ? s4.z : s4.w;
        const unsigned int cv = (r == 0) ? c4.x : (r == 1) ? c4.y : (r == 2) ? c4.z : c4.w;
        Gr[mm] += s * lo_f(cv);
        Gi[mm] += s * hi_f(cv);
        ++pair;
      }
    }
  }
  DEF_TRIG;
#pragma unroll
  for (int pp = 0; pp <= 16; ++pp) {
    float A = 0.f, Bv = 0.f;
#pragma unroll
    for (int mm = 0; mm < 16; ++mm) {
      A  += Gr[mm] * CT[(mm * pp) & 31];
      Bv += Gi[mm] * ST[(mm * pp) & 31];
    }
    const int p2 = (32 - pp) & 31;
    size_t e1 = (size_t)b * 131072 + (size_t)(j * 32 + pp) * 128 + o;
    size_t e2 = (size_t)b * 131072 + (size_t)(j * 32 + p2) * 128 + o;
    if (fp32m) {
      *(float*)(outbuf + e1 * 4) = bv + A - Bv;
      *(float*)(outbuf + e2 * 4) = bv + A + Bv;
    } else {
      *(unsigned short*)(outbuf + e1 * 2) = f2us(bv + A - Bv);
      *(unsigned short*)(outbuf + e2 * 2) = f2us(bv + A + Bv);
    }
  }
}

// ---------------------------------------------------------------------------
extern "C" void kernel_launch(void* const* d_in, const int* in_sizes, int n_in,
                              void* d_out, int out_size, void* d_ws, size_t ws_size,
                              hipStream_t stream) {
  const void* xin  = d_in[0];   // (64,32,32,128) fp32 or bf16 (auto-detected)
  const void* W    = d_in[1];   // (128,16,128)
  const void* bias = d_in[2];   // (128)
  char* out = (char*)d_out;
  unsigned int* ws = (unsigned int*)d_ws;  // re@0, im@4MB, Wt@8MB

  hipLaunchKernelGGL(k_fwd, dim3(1024), dim3(256),  0, stream, xin, ws, W);
  hipLaunchKernelGGL(k_cb,  dim3(256),  dim3(1024), 0, stream, ws, out, bias, xin);
}